// Round 6
// baseline (371.311 us; speedup 1.0000x reference)
//
#include <hip/hip_runtime.h>

#define EPS 1e-5f
#define BATCH 16
#define LEN   1024
#define NF1   100
#define NF2   128
#define NB    256
#define NT    512

// workspace float offsets
#define OFF_BAR   0        // 3 ints used, one 128B line reserved
#define OFF_S1    32       // 32
#define OFF_Q1    64       // 32
#define OFF_S2    96       // 64
#define OFF_Q2    160      // 64
#define OFF_ZZ    256      // 16*100 = 1600 (ends 1856)
#define OFF_C1    2048     // [n][ch][l] 16*32*1024
#define OFF_C2T   526336   // [n][l][k]  16*1024*64
#define ZERO_FLOATS 1856

// R2-proven fenced grid barrier (all NB blocks co-resident: NB == #CUs).
__device__ __forceinline__ void grid_barrier(int* cnt) {
    __syncthreads();
    if (threadIdx.x == 0) {
        __threadfence();
        __hip_atomic_fetch_add(cnt, 1, __ATOMIC_ACQ_REL, __HIP_MEMORY_SCOPE_AGENT);
        while (__hip_atomic_load(cnt, __ATOMIC_ACQUIRE, __HIP_MEMORY_SCOPE_AGENT) < NB)
            __builtin_amdgcn_s_sleep(2);
        __threadfence();
    }
    __syncthreads();
}

__global__ __launch_bounds__(NT, 2)
void fused_all(const float* __restrict__ x, const float* __restrict__ bmat,
               const float* __restrict__ c1w, const float* __restrict__ c1b,
               const float* __restrict__ g1, const float* __restrict__ bb1,
               const float* __restrict__ c2w, const float* __restrict__ c2b,
               const float* __restrict__ g2, const float* __restrict__ bb2,
               const float* __restrict__ w1, const float* __restrict__ b1f,
               const float* __restrict__ g3, const float* __restrict__ b3,
               const float* __restrict__ w2, const float* __restrict__ b2f,
               float* __restrict__ out, float* __restrict__ ws) {
    int* bar   = (int*)(ws + OFF_BAR);
    float* c1  = ws + OFF_C1;
    float* c2t = ws + OFF_C2T;

    __shared__ __align__(16) float smem[9856];   // 39.4 KB peak (phase 3)

    const int tid  = threadIdx.x;
    const int bid  = blockIdx.x;
    const int lane = tid & 63;
    const int wave = __builtin_amdgcn_readfirstlane(tid >> 6);

    // ========== Phase 1: conv1 (8->32,K5,pad2)+bias -> c1, BN1 stats ==========
    {
        int n = bid >> 4, lt = bid & 15;
        int l0 = lt * 64;
        float* xs = smem;                          // [8 ci][72]
        if (tid < 136) {
            int r = tid >> 1, cq = tid & 1;
            int lr = l0 - 2 + r;
            float4 v = make_float4(0.f, 0.f, 0.f, 0.f);
            if (lr >= 0 && lr < LEN)
                v = *(const float4*)(x + ((size_t)n * LEN + lr) * 8 + cq * 4);
            xs[(cq*4+0)*72 + r] = v.x;
            xs[(cq*4+1)*72 + r] = v.y;
            xs[(cq*4+2)*72 + r] = v.z;
            xs[(cq*4+3)*72 + r] = v.w;
        }
        __syncthreads();
        int ch0 = wave * 4;                        // 8 waves x 4 ch = 32
        float a[4];
#pragma unroll
        for (int u = 0; u < 4; ++u) a[u] = c1b[ch0 + u];
#pragma unroll
        for (int ci = 0; ci < 8; ++ci)
#pragma unroll
            for (int d = 0; d < 5; ++d) {
                float xv = xs[ci*72 + lane + d];
#pragma unroll
                for (int u = 0; u < 4; ++u)
                    a[u] += xv * c1w[(ch0 + u)*40 + ci*5 + d];
            }
#pragma unroll
        for (int u = 0; u < 4; ++u)
            c1[((size_t)n*32 + ch0 + u)*LEN + l0 + lane] = a[u];
#pragma unroll
        for (int u = 0; u < 4; ++u) {
            float s = a[u], q = a[u]*a[u];
#pragma unroll
            for (int off = 32; off >= 1; off >>= 1) {
                s += __shfl_xor(s, off); q += __shfl_xor(q, off);
            }
            if (lane == 0) {
                atomicAdd(&ws[OFF_S1 + ch0 + u], s);
                atomicAdd(&ws[OFF_Q1 + ch0 + u], q);
            }
        }
    }
    grid_barrier(&bar[0]);

    // ========== Phase 2: BN1+ReLU -> conv2 (32->64,K5) -> c2t [n][l][k], BN2 stats ==========
    {
        int n = bid >> 4, lt = bid & 15;
        int l0 = lt * 64;
        float* sc1 = smem;                         // 32
        float* sh1 = smem + 32;                    // 32
        float* a1  = smem + 64;                    // [32 ci][72]
        float* st2 = smem + 2368;                  // [64 l][68]
        if (tid < 32) {
            float s = ws[OFF_S1 + tid], q = ws[OFF_Q1 + tid];
            float mean = s * (1.f/16384.f);
            float var  = q * (1.f/16384.f) - mean*mean;
            float rs = rsqrtf(var + EPS);
            float sc = g1[tid] * rs;
            sc1[tid] = sc; sh1[tid] = bb1[tid] - mean * sc;
        }
        __syncthreads();
        for (int p = tid; p < 32*72; p += NT) {
            int ci = p / 72, lo = p - ci*72;
            int lg = l0 - 4 + lo;
            float v = (lg >= 0 && lg < LEN) ? c1[((size_t)n*32 + ci)*LEN + lg] : 0.f;
            a1[p] = fmaxf(0.f, v * sc1[ci] + sh1[ci]);
        }
        __syncthreads();
        int co0 = wave * 8;                        // 8 waves x 8 co = 64
        float acc[8];
#pragma unroll
        for (int u = 0; u < 8; ++u) acc[u] = c2b[co0 + u];
        for (int ci = 0; ci < 32; ++ci) {
            float xv[5];
#pragma unroll
            for (int d = 0; d < 5; ++d) xv[d] = a1[ci*72 + lane + 2 + d];
#pragma unroll
            for (int u = 0; u < 8; ++u) {
                const float* wp = c2w + ((size_t)(co0 + u)*32 + ci)*5;  // wave-uniform
                acc[u] += xv[0]*wp[0] + xv[1]*wp[1] + xv[2]*wp[2] + xv[3]*wp[3] + xv[4]*wp[4];
            }
        }
#pragma unroll
        for (int u = 0; u < 8; ++u) {
            float s = acc[u], q = acc[u]*acc[u];
#pragma unroll
            for (int off = 32; off >= 1; off >>= 1) {
                s += __shfl_xor(s, off); q += __shfl_xor(q, off);
            }
            if (lane == 0) {
                atomicAdd(&ws[OFF_S2 + co0 + u], s);
                atomicAdd(&ws[OFF_Q2 + co0 + u], q);
            }
        }
        *(float4*)&st2[lane*68 + co0]     = make_float4(acc[0], acc[1], acc[2], acc[3]);
        *(float4*)&st2[lane*68 + co0 + 4] = make_float4(acc[4], acc[5], acc[6], acc[7]);
        __syncthreads();
        {
            int lr = tid >> 3, qq = tid & 7;
            float4 va = *(float4*)&st2[lr*68 + qq*8];
            float4 vb = *(float4*)&st2[lr*68 + qq*8 + 4];
            float* dst = c2t + ((size_t)n*LEN + l0 + lr)*64 + qq*8;
            *(float4*)dst = va;
            *(float4*)(dst + 4) = vb;
        }
    }
    grid_barrier(&bar[1]);

    // ========== Phase 3: BN2+ReLU + max-product pool (full i) + FC1 partials -> zz ==========
    {
        int n = bid & 15, jt = bid >> 4;           // bid%8 = n%8 -> c2t[n] XCD-local
        int j0 = jt * 8;
        float* sc2 = smem;                         // 64
        float* sh2 = smem + 64;                    // 64
        float* bt  = smem + 128;                   // 2 x [64][8]
        float* ht  = smem + 1152;                  // 2 x [64][68]
        float* red = ht;                           // overlay 4608 <= 8704
        float* zlf = bt;                           // overlay 512 <= 1024
        if (tid < 64) {
            float s = ws[OFF_S2 + tid], q = ws[OFF_Q2 + tid];
            float mean = s * (1.f/16384.f);
            float var  = q * (1.f/16384.f) - mean*mean;
            float rs = rsqrtf(var + EPS);
            float sc = g2[tid] * rs;
            sc2[tid] = sc; sh2[tid] = bb2[tid] - mean * sc;
        }
        __syncthreads();

        int irh = tid >> 3, kq8 = tid & 7;         // staging: 64 rows x 8 groups
        float sck[8], shk[8];
#pragma unroll
        for (int e = 0; e < 8; ++e) { sck[e] = sc2[kq8*8 + e]; shk[e] = sh2[kq8*8 + e]; }

        const float* c2base = c2t + (size_t)n * LEN * 64;
        const float* bbase  = bmat + (size_t)n * LEN * 128 + j0;

        // preload + stage chunk 0
        float4 ha = *(const float4*)(c2base + (size_t)irh*64 + kq8*8);
        float4 hb = *(const float4*)(c2base + (size_t)irh*64 + kq8*8 + 4);
        float bv  = bbase[(size_t)irh*128 + kq8];
        {
            float4 ra, rb;
            ra.x = fmaxf(0.f, ha.x*sck[0]+shk[0]); ra.y = fmaxf(0.f, ha.y*sck[1]+shk[1]);
            ra.z = fmaxf(0.f, ha.z*sck[2]+shk[2]); ra.w = fmaxf(0.f, ha.w*sck[3]+shk[3]);
            rb.x = fmaxf(0.f, hb.x*sck[4]+shk[4]); rb.y = fmaxf(0.f, hb.y*sck[5]+shk[5]);
            rb.z = fmaxf(0.f, hb.z*sck[6]+shk[6]); rb.w = fmaxf(0.f, hb.w*sck[7]+shk[7]);
            *(float4*)&ht[irh*68 + kq8*8]     = ra;
            *(float4*)&ht[irh*68 + kq8*8 + 4] = rb;
            bt[irh*8 + kq8] = bv;
        }
        __syncthreads();

        int s_low = lane >> 5, jh = (lane >> 4) & 1, kq = lane & 15;
        int sl = wave * 2 + s_low;                 // 16 i-slices of 4
        float mx[4][4];
#pragma unroll
        for (int a2 = 0; a2 < 4; ++a2)
#pragma unroll
            for (int cc = 0; cc < 4; ++cc) mx[a2][cc] = 0.f;

        for (int c = 0; c < 16; ++c) {
            int buf = c & 1;
            if (c < 15) {
                int ib = (c + 1) * 64;
                ha = *(const float4*)(c2base + (size_t)(ib + irh)*64 + kq8*8);
                hb = *(const float4*)(c2base + (size_t)(ib + irh)*64 + kq8*8 + 4);
                bv = bbase[(size_t)(ib + irh)*128 + kq8];
            }
            const float* btc = bt + buf*512;
            const float* htc = ht + buf*4352;
#pragma unroll
            for (int ii = 0; ii < 4; ++ii) {
                int row = sl*4 + ii;
                float4 bq = *(const float4*)&btc[row*8 + jh*4];
                float4 hq = *(const float4*)&htc[row*68 + kq*4];
                float bb_[4] = {bq.x, bq.y, bq.z, bq.w};
                float hh_[4] = {hq.x, hq.y, hq.z, hq.w};
#pragma unroll
                for (int a2 = 0; a2 < 4; ++a2)
#pragma unroll
                    for (int cc = 0; cc < 4; ++cc)
                        mx[a2][cc] = fmaxf(mx[a2][cc], bb_[a2] * hh_[cc]);
            }
            if (c < 15) {
                int nb_ = buf ^ 1;
                float* htn = ht + nb_*4352;
                float* btn = bt + nb_*512;
                float4 ra, rb;
                ra.x = fmaxf(0.f, ha.x*sck[0]+shk[0]); ra.y = fmaxf(0.f, ha.y*sck[1]+shk[1]);
                ra.z = fmaxf(0.f, ha.z*sck[2]+shk[2]); ra.w = fmaxf(0.f, ha.w*sck[3]+shk[3]);
                rb.x = fmaxf(0.f, hb.x*sck[4]+shk[4]); rb.y = fmaxf(0.f, hb.y*sck[5]+shk[5]);
                rb.z = fmaxf(0.f, hb.z*sck[6]+shk[6]); rb.w = fmaxf(0.f, hb.w*sck[7]+shk[7]);
                *(float4*)&htn[irh*68 + kq8*8]     = ra;
                *(float4*)&htn[irh*68 + kq8*8 + 4] = rb;
                btn[irh*8 + kq8] = bv;
            }
            __syncthreads();
        }

        // reduce over 16 i-slices: in-wave (xor 32), then 8 waves via LDS
#pragma unroll
        for (int a2 = 0; a2 < 4; ++a2)
#pragma unroll
            for (int cc = 0; cc < 4; ++cc)
                mx[a2][cc] = fmaxf(mx[a2][cc], __shfl_xor(mx[a2][cc], 32));
        if (lane < 32) {
            int base = (wave*32 + lane)*18;        // stride 18 breaks bank alignment
#pragma unroll
            for (int a2 = 0; a2 < 4; ++a2)
#pragma unroll
                for (int cc = 0; cc < 4; ++cc)
                    red[base + a2*4 + cc] = mx[a2][cc];
        }
        __syncthreads();
        {
            int z = tid;                           // z = j*64 + k
            int j = z >> 6, k = z & 63;
            int g = (j >> 2)*16 + (k >> 2);
            int e = (j & 3)*4 + (k & 3);
            float m = 0.f;
#pragma unroll
            for (int w8 = 0; w8 < 8; ++w8)
                m = fmaxf(m, red[(w8*32 + g)*18 + e]);
            zlf[z] = m;
        }
        __syncthreads();
        // FC1 partial: zz[n][f] += w1[f][j0*64 .. j0*64+512) . zlf
        for (int f = wave; f < NF1; f += 8) {
            const float* wrow = w1 + (size_t)f*8192 + j0*64;
            float4 wa = *(const float4*)(wrow + lane*8);
            float4 wb = *(const float4*)(wrow + lane*8 + 4);
            float4 za = *(const float4*)&zlf[lane*8];
            float4 zb = *(const float4*)&zlf[lane*8 + 4];
            float acc = wa.x*za.x + wa.y*za.y + wa.z*za.z + wa.w*za.w
                      + wb.x*zb.x + wb.y*zb.y + wb.z*zb.z + wb.w*zb.w;
#pragma unroll
            for (int off = 32; off >= 1; off >>= 1) acc += __shfl_xor(acc, off);
            if (lane == 0) atomicAdd(&ws[OFF_ZZ + n*NF1 + f], acc);
        }
    }
    grid_barrier(&bar[2]);

    // ========== Phase 4: +b1, BN3 over batch, ReLU, FC2 -> out (16 blocks) ==========
    if (bid < 16) {
        int n = bid;
        float* zzl  = smem;                        // 1600
        float* sc3  = smem + 1600;                 // 100
        float* sh3  = smem + 1700;                 // 100
        float* red2 = smem + 1824;                 // [4][128]
        for (int idx = tid; idx < BATCH*NF1; idx += NT) {
            int f = idx % NF1;
            zzl[idx] = ws[OFF_ZZ + idx] + b1f[f];
        }
        __syncthreads();
        if (tid < NF1) {
            float s = 0.f, q = 0.f;
#pragma unroll
            for (int m = 0; m < BATCH; ++m) {
                float v = zzl[m*NF1 + tid];
                s += v; q += v*v;
            }
            float mean = s * (1.f/16.f);
            float var  = q * (1.f/16.f) - mean*mean;
            float rs = rsqrtf(var + EPS);
            float sc = g3[tid] * rs;
            sc3[tid] = sc; sh3[tid] = b3[tid] - mean * sc;
        }
        __syncthreads();
        for (int idx = tid; idx < BATCH*NF1; idx += NT) {
            int f = idx % NF1;
            zzl[idx] = fmaxf(0.f, zzl[idx]*sc3[f] + sh3[f]);
        }
        __syncthreads();
        {
            int o = tid & 127, fp = tid >> 7;      // 4 f-phases x 128 outputs
            float acc = 0.f;
            for (int f = fp; f < NF1; f += 4)
                acc += zzl[n*NF1 + f] * w2[(size_t)o*NF1 + f];
            red2[fp*128 + o] = acc;
        }
        __syncthreads();
        if (tid < 128) {
            float v = b2f[tid];
#pragma unroll
            for (int p = 0; p < 4; ++p) v += red2[p*128 + tid];
            out[n*NF2 + tid] = v;
        }
    }
}

extern "C" void kernel_launch(void* const* d_in, const int* in_sizes, int n_in,
                              void* d_out, int out_size, void* d_ws, size_t ws_size,
                              hipStream_t stream) {
    const float* x    = (const float*)d_in[0];
    const float* bmat = (const float*)d_in[1];
    const float* c1w  = (const float*)d_in[2];
    const float* c1b  = (const float*)d_in[3];
    const float* g1   = (const float*)d_in[4];
    const float* bb1  = (const float*)d_in[5];
    const float* c2w  = (const float*)d_in[6];
    const float* c2b  = (const float*)d_in[7];
    const float* g2   = (const float*)d_in[8];
    const float* bb2  = (const float*)d_in[9];
    const float* w1   = (const float*)d_in[10];
    const float* b1   = (const float*)d_in[11];
    const float* g3   = (const float*)d_in[12];
    const float* b3   = (const float*)d_in[13];
    const float* w2   = (const float*)d_in[14];
    const float* b2   = (const float*)d_in[15];
    float* out = (float*)d_out;
    float* ws  = (float*)d_ws;

    (void)hipMemsetAsync(ws, 0, ZERO_FLOATS * sizeof(float), stream);
    fused_all<<<NB, NT, 0, stream>>>(x, bmat, c1w, c1b, g1, bb1, c2w, c2b,
                                     g2, bb2, w1, b1, g3, b3, w2, b2, out, ws);
}

// Round 7
// 336.139 us; speedup vs baseline: 1.1046x; 1.1046x over previous
//
#include <hip/hip_runtime.h>

#define EPS 1e-5f
#define BATCH 16
#define LEN   1024
#define NF1   100
#define NF2   128
#define NB    256
#define NT    512

// workspace float offsets
#define OFF_BAR   0        // 3 ints used, one 128B line reserved
#define OFF_S1    32       // 32
#define OFF_Q1    64       // 32
#define OFF_S2    96       // 64
#define OFF_Q2    160      // 64
#define OFF_ZZ    256      // 16*100 = 1600 (ends 1856)
#define OFF_C1    2048     // [n][ch][l] 16*32*1024
#define OFF_C2T   526336   // [n][l][k]  16*1024*64
#define ZERO_FLOATS 1856

// Grid barrier, storm-free version. The R6 barrier spun on an ACQUIRE load:
// every iteration emits buffer_inv (XCD-wide L2 invalidate), so 256 spinning
// blocks continuously wiped L2 for all still-working blocks (~95% stall).
// Here: one release fence (wbl2) before arrive, RELAXED spin (plain coherent
// load, no cache maintenance), one acquire fence (inv) after exit.
__device__ __forceinline__ void grid_barrier(int* cnt) {
    __syncthreads();
    if (threadIdx.x == 0) {
        __builtin_amdgcn_fence(__ATOMIC_RELEASE, "agent");
        __hip_atomic_fetch_add(cnt, 1, __ATOMIC_RELAXED, __HIP_MEMORY_SCOPE_AGENT);
        while (__hip_atomic_load(cnt, __ATOMIC_RELAXED, __HIP_MEMORY_SCOPE_AGENT) < NB)
            __builtin_amdgcn_s_sleep(8);
        __builtin_amdgcn_fence(__ATOMIC_ACQUIRE, "agent");
    }
    __syncthreads();
}

__global__ __launch_bounds__(NT, 2)
void fused_all(const float* __restrict__ x, const float* __restrict__ bmat,
               const float* __restrict__ c1w, const float* __restrict__ c1b,
               const float* __restrict__ g1, const float* __restrict__ bb1,
               const float* __restrict__ c2w, const float* __restrict__ c2b,
               const float* __restrict__ g2, const float* __restrict__ bb2,
               const float* __restrict__ w1, const float* __restrict__ b1f,
               const float* __restrict__ g3, const float* __restrict__ b3,
               const float* __restrict__ w2, const float* __restrict__ b2f,
               float* __restrict__ out, float* __restrict__ ws) {
    int* bar   = (int*)(ws + OFF_BAR);
    float* c1  = ws + OFF_C1;
    float* c2t = ws + OFF_C2T;

    __shared__ __align__(16) float smem[9856];   // 39.4 KB peak (phase 3)

    const int tid  = threadIdx.x;
    const int bid  = blockIdx.x;
    const int lane = tid & 63;
    const int wave = __builtin_amdgcn_readfirstlane(tid >> 6);

    // ========== Phase 1: conv1 (8->32,K5,pad2)+bias -> c1, BN1 stats ==========
    {
        int n = bid >> 4, lt = bid & 15;
        int l0 = lt * 64;
        float* xs = smem;                          // [8 ci][72]
        if (tid < 136) {
            int r = tid >> 1, cq = tid & 1;
            int lr = l0 - 2 + r;
            float4 v = make_float4(0.f, 0.f, 0.f, 0.f);
            if (lr >= 0 && lr < LEN)
                v = *(const float4*)(x + ((size_t)n * LEN + lr) * 8 + cq * 4);
            xs[(cq*4+0)*72 + r] = v.x;
            xs[(cq*4+1)*72 + r] = v.y;
            xs[(cq*4+2)*72 + r] = v.z;
            xs[(cq*4+3)*72 + r] = v.w;
        }
        __syncthreads();
        int ch0 = wave * 4;                        // 8 waves x 4 ch = 32
        float a[4];
#pragma unroll
        for (int u = 0; u < 4; ++u) a[u] = c1b[ch0 + u];
#pragma unroll
        for (int ci = 0; ci < 8; ++ci)
#pragma unroll
            for (int d = 0; d < 5; ++d) {
                float xv = xs[ci*72 + lane + d];
#pragma unroll
                for (int u = 0; u < 4; ++u)
                    a[u] += xv * c1w[(ch0 + u)*40 + ci*5 + d];
            }
#pragma unroll
        for (int u = 0; u < 4; ++u)
            c1[((size_t)n*32 + ch0 + u)*LEN + l0 + lane] = a[u];
#pragma unroll
        for (int u = 0; u < 4; ++u) {
            float s = a[u], q = a[u]*a[u];
#pragma unroll
            for (int off = 32; off >= 1; off >>= 1) {
                s += __shfl_xor(s, off); q += __shfl_xor(q, off);
            }
            if (lane == 0) {
                atomicAdd(&ws[OFF_S1 + ch0 + u], s);
                atomicAdd(&ws[OFF_Q1 + ch0 + u], q);
            }
        }
    }
    grid_barrier(&bar[0]);

    // ========== Phase 2: BN1+ReLU -> conv2 (32->64,K5) -> c2t [n][l][k], BN2 stats ==========
    {
        int n = bid >> 4, lt = bid & 15;
        int l0 = lt * 64;
        float* sc1 = smem;                         // 32
        float* sh1 = smem + 32;                    // 32
        float* a1  = smem + 64;                    // [32 ci][72]
        float* st2 = smem + 2368;                  // [64 l][68]
        if (tid < 32) {
            float s = ws[OFF_S1 + tid], q = ws[OFF_Q1 + tid];
            float mean = s * (1.f/16384.f);
            float var  = q * (1.f/16384.f) - mean*mean;
            float rs = rsqrtf(var + EPS);
            float sc = g1[tid] * rs;
            sc1[tid] = sc; sh1[tid] = bb1[tid] - mean * sc;
        }
        __syncthreads();
        for (int p = tid; p < 32*72; p += NT) {
            int ci = p / 72, lo = p - ci*72;
            int lg = l0 - 4 + lo;
            float v = (lg >= 0 && lg < LEN) ? c1[((size_t)n*32 + ci)*LEN + lg] : 0.f;
            a1[p] = fmaxf(0.f, v * sc1[ci] + sh1[ci]);
        }
        __syncthreads();
        int co0 = wave * 8;                        // 8 waves x 8 co = 64
        float acc[8];
#pragma unroll
        for (int u = 0; u < 8; ++u) acc[u] = c2b[co0 + u];
        for (int ci = 0; ci < 32; ++ci) {
            float xv[5];
#pragma unroll
            for (int d = 0; d < 5; ++d) xv[d] = a1[ci*72 + lane + 2 + d];
#pragma unroll
            for (int u = 0; u < 8; ++u) {
                const float* wp = c2w + ((size_t)(co0 + u)*32 + ci)*5;  // wave-uniform
                acc[u] += xv[0]*wp[0] + xv[1]*wp[1] + xv[2]*wp[2] + xv[3]*wp[3] + xv[4]*wp[4];
            }
        }
#pragma unroll
        for (int u = 0; u < 8; ++u) {
            float s = acc[u], q = acc[u]*acc[u];
#pragma unroll
            for (int off = 32; off >= 1; off >>= 1) {
                s += __shfl_xor(s, off); q += __shfl_xor(q, off);
            }
            if (lane == 0) {
                atomicAdd(&ws[OFF_S2 + co0 + u], s);
                atomicAdd(&ws[OFF_Q2 + co0 + u], q);
            }
        }
        *(float4*)&st2[lane*68 + co0]     = make_float4(acc[0], acc[1], acc[2], acc[3]);
        *(float4*)&st2[lane*68 + co0 + 4] = make_float4(acc[4], acc[5], acc[6], acc[7]);
        __syncthreads();
        {
            int lr = tid >> 3, qq = tid & 7;
            float4 va = *(float4*)&st2[lr*68 + qq*8];
            float4 vb = *(float4*)&st2[lr*68 + qq*8 + 4];
            float* dst = c2t + ((size_t)n*LEN + l0 + lr)*64 + qq*8;
            *(float4*)dst = va;
            *(float4*)(dst + 4) = vb;
        }
    }
    grid_barrier(&bar[1]);

    // ========== Phase 3: BN2+ReLU + max-product pool (full i) + FC1 partials -> zz ==========
    {
        int n = bid & 15, jt = bid >> 4;           // bid%8 = n%8 -> c2t[n] XCD-local
        int j0 = jt * 8;
        float* sc2 = smem;                         // 64
        float* sh2 = smem + 64;                    // 64
        float* bt  = smem + 128;                   // 2 x [64][8]
        float* ht  = smem + 1152;                  // 2 x [64][68]
        float* red = ht;                           // overlay 4608 <= 8704
        float* zlf = bt;                           // overlay 512 <= 1024
        if (tid < 64) {
            float s = ws[OFF_S2 + tid], q = ws[OFF_Q2 + tid];
            float mean = s * (1.f/16384.f);
            float var  = q * (1.f/16384.f) - mean*mean;
            float rs = rsqrtf(var + EPS);
            float sc = g2[tid] * rs;
            sc2[tid] = sc; sh2[tid] = bb2[tid] - mean * sc;
        }
        __syncthreads();

        int irh = tid >> 3, kq8 = tid & 7;         // staging: 64 rows x 8 groups
        float sck[8], shk[8];
#pragma unroll
        for (int e = 0; e < 8; ++e) { sck[e] = sc2[kq8*8 + e]; shk[e] = sh2[kq8*8 + e]; }

        const float* c2base = c2t + (size_t)n * LEN * 64;
        const float* bbase  = bmat + (size_t)n * LEN * 128 + j0;

        // preload + stage chunk 0
        float4 ha = *(const float4*)(c2base + (size_t)irh*64 + kq8*8);
        float4 hb = *(const float4*)(c2base + (size_t)irh*64 + kq8*8 + 4);
        float bv  = bbase[(size_t)irh*128 + kq8];
        {
            float4 ra, rb;
            ra.x = fmaxf(0.f, ha.x*sck[0]+shk[0]); ra.y = fmaxf(0.f, ha.y*sck[1]+shk[1]);
            ra.z = fmaxf(0.f, ha.z*sck[2]+shk[2]); ra.w = fmaxf(0.f, ha.w*sck[3]+shk[3]);
            rb.x = fmaxf(0.f, hb.x*sck[4]+shk[4]); rb.y = fmaxf(0.f, hb.y*sck[5]+shk[5]);
            rb.z = fmaxf(0.f, hb.z*sck[6]+shk[6]); rb.w = fmaxf(0.f, hb.w*sck[7]+shk[7]);
            *(float4*)&ht[irh*68 + kq8*8]     = ra;
            *(float4*)&ht[irh*68 + kq8*8 + 4] = rb;
            bt[irh*8 + kq8] = bv;
        }
        __syncthreads();

        int s_low = lane >> 5, jh = (lane >> 4) & 1, kq = lane & 15;
        int sl = wave * 2 + s_low;                 // 16 i-slices of 4
        float mx[4][4];
#pragma unroll
        for (int a2 = 0; a2 < 4; ++a2)
#pragma unroll
            for (int cc = 0; cc < 4; ++cc) mx[a2][cc] = 0.f;

        for (int c = 0; c < 16; ++c) {
            int buf = c & 1;
            if (c < 15) {
                int ib = (c + 1) * 64;
                ha = *(const float4*)(c2base + (size_t)(ib + irh)*64 + kq8*8);
                hb = *(const float4*)(c2base + (size_t)(ib + irh)*64 + kq8*8 + 4);
                bv = bbase[(size_t)(ib + irh)*128 + kq8];
            }
            const float* btc = bt + buf*512;
            const float* htc = ht + buf*4352;
#pragma unroll
            for (int ii = 0; ii < 4; ++ii) {
                int row = sl*4 + ii;
                float4 bq = *(const float4*)&btc[row*8 + jh*4];
                float4 hq = *(const float4*)&htc[row*68 + kq*4];
                float bb_[4] = {bq.x, bq.y, bq.z, bq.w};
                float hh_[4] = {hq.x, hq.y, hq.z, hq.w};
#pragma unroll
                for (int a2 = 0; a2 < 4; ++a2)
#pragma unroll
                    for (int cc = 0; cc < 4; ++cc)
                        mx[a2][cc] = fmaxf(mx[a2][cc], bb_[a2] * hh_[cc]);
            }
            if (c < 15) {
                int nb_ = buf ^ 1;
                float* htn = ht + nb_*4352;
                float* btn = bt + nb_*512;
                float4 ra, rb;
                ra.x = fmaxf(0.f, ha.x*sck[0]+shk[0]); ra.y = fmaxf(0.f, ha.y*sck[1]+shk[1]);
                ra.z = fmaxf(0.f, ha.z*sck[2]+shk[2]); ra.w = fmaxf(0.f, ha.w*sck[3]+shk[3]);
                rb.x = fmaxf(0.f, hb.x*sck[4]+shk[4]); rb.y = fmaxf(0.f, hb.y*sck[5]+shk[5]);
                rb.z = fmaxf(0.f, hb.z*sck[6]+shk[6]); rb.w = fmaxf(0.f, hb.w*sck[7]+shk[7]);
                *(float4*)&htn[irh*68 + kq8*8]     = ra;
                *(float4*)&htn[irh*68 + kq8*8 + 4] = rb;
                btn[irh*8 + kq8] = bv;
            }
            __syncthreads();
        }

        // reduce over 16 i-slices: in-wave (xor 32), then 8 waves via LDS
#pragma unroll
        for (int a2 = 0; a2 < 4; ++a2)
#pragma unroll
            for (int cc = 0; cc < 4; ++cc)
                mx[a2][cc] = fmaxf(mx[a2][cc], __shfl_xor(mx[a2][cc], 32));
        if (lane < 32) {
            int base = (wave*32 + lane)*18;        // stride 18 breaks bank alignment
#pragma unroll
            for (int a2 = 0; a2 < 4; ++a2)
#pragma unroll
                for (int cc = 0; cc < 4; ++cc)
                    red[base + a2*4 + cc] = mx[a2][cc];
        }
        __syncthreads();
        {
            int z = tid;                           // z = j*64 + k
            int j = z >> 6, k = z & 63;
            int g = (j >> 2)*16 + (k >> 2);
            int e = (j & 3)*4 + (k & 3);
            float m = 0.f;
#pragma unroll
            for (int w8 = 0; w8 < 8; ++w8)
                m = fmaxf(m, red[(w8*32 + g)*18 + e]);
            zlf[z] = m;
        }
        __syncthreads();
        // FC1 partial: zz[n][f] += w1[f][j0*64 .. j0*64+512) . zlf
        for (int f = wave; f < NF1; f += 8) {
            const float* wrow = w1 + (size_t)f*8192 + j0*64;
            float4 wa = *(const float4*)(wrow + lane*8);
            float4 wb = *(const float4*)(wrow + lane*8 + 4);
            float4 za = *(const float4*)&zlf[lane*8];
            float4 zb = *(const float4*)&zlf[lane*8 + 4];
            float acc = wa.x*za.x + wa.y*za.y + wa.z*za.z + wa.w*za.w
                      + wb.x*zb.x + wb.y*zb.y + wb.z*zb.z + wb.w*zb.w;
#pragma unroll
            for (int off = 32; off >= 1; off >>= 1) acc += __shfl_xor(acc, off);
            if (lane == 0) atomicAdd(&ws[OFF_ZZ + n*NF1 + f], acc);
        }
    }
    grid_barrier(&bar[2]);

    // ========== Phase 4: +b1, BN3 over batch, ReLU, FC2 -> out (16 blocks) ==========
    if (bid < 16) {
        int n = bid;
        float* zzl  = smem;                        // 1600
        float* sc3  = smem + 1600;                 // 100
        float* sh3  = smem + 1700;                 // 100
        float* red2 = smem + 1824;                 // [4][128]
        for (int idx = tid; idx < BATCH*NF1; idx += NT) {
            int f = idx % NF1;
            zzl[idx] = ws[OFF_ZZ + idx] + b1f[f];
        }
        __syncthreads();
        if (tid < NF1) {
            float s = 0.f, q = 0.f;
#pragma unroll
            for (int m = 0; m < BATCH; ++m) {
                float v = zzl[m*NF1 + tid];
                s += v; q += v*v;
            }
            float mean = s * (1.f/16.f);
            float var  = q * (1.f/16.f) - mean*mean;
            float rs = rsqrtf(var + EPS);
            float sc = g3[tid] * rs;
            sc3[tid] = sc; sh3[tid] = b3[tid] - mean * sc;
        }
        __syncthreads();
        for (int idx = tid; idx < BATCH*NF1; idx += NT) {
            int f = idx % NF1;
            zzl[idx] = fmaxf(0.f, zzl[idx]*sc3[f] + sh3[f]);
        }
        __syncthreads();
        {
            int o = tid & 127, fp = tid >> 7;      // 4 f-phases x 128 outputs
            float acc = 0.f;
            for (int f = fp; f < NF1; f += 4)
                acc += zzl[n*NF1 + f] * w2[(size_t)o*NF1 + f];
            red2[fp*128 + o] = acc;
        }
        __syncthreads();
        if (tid < 128) {
            float v = b2f[tid];
#pragma unroll
            for (int p = 0; p < 4; ++p) v += red2[p*128 + tid];
            out[n*NF2 + tid] = v;
        }
    }
}

extern "C" void kernel_launch(void* const* d_in, const int* in_sizes, int n_in,
                              void* d_out, int out_size, void* d_ws, size_t ws_size,
                              hipStream_t stream) {
    const float* x    = (const float*)d_in[0];
    const float* bmat = (const float*)d_in[1];
    const float* c1w  = (const float*)d_in[2];
    const float* c1b  = (const float*)d_in[3];
    const float* g1   = (const float*)d_in[4];
    const float* bb1  = (const float*)d_in[5];
    const float* c2w  = (const float*)d_in[6];
    const float* c2b  = (const float*)d_in[7];
    const float* g2   = (const float*)d_in[8];
    const float* bb2  = (const float*)d_in[9];
    const float* w1   = (const float*)d_in[10];
    const float* b1   = (const float*)d_in[11];
    const float* g3   = (const float*)d_in[12];
    const float* b3   = (const float*)d_in[13];
    const float* w2   = (const float*)d_in[14];
    const float* b2   = (const float*)d_in[15];
    float* out = (float*)d_out;
    float* ws  = (float*)d_ws;

    (void)hipMemsetAsync(ws, 0, ZERO_FLOATS * sizeof(float), stream);
    fused_all<<<NB, NT, 0, stream>>>(x, bmat, c1w, c1b, g1, bb1, c2w, c2b,
                                     g2, bb2, w1, b1, g3, b3, w2, b2, out, ws);
}